// Round 5
// baseline (432.843 us; speedup 1.0000x reference)
//
#include <hip/hip_runtime.h>
#include <hip/hip_bf16.h>

typedef __attribute__((ext_vector_type(8))) short short8;
typedef __attribute__((ext_vector_type(4))) float f32x4;

typedef const __attribute__((address_space(1))) void* as1cv_t;
typedef __attribute__((address_space(3))) void* as3v_t;
typedef __attribute__((address_space(3))) const char* as3cc_t;
typedef __attribute__((address_space(3))) const short8* as3s8_t;

__device__ __forceinline__ unsigned short f2bf(float f) {
    unsigned u = __float_as_uint(f);
    u += 0x7fffu + ((u >> 16) & 1u);   // round-to-nearest-even
    return (unsigned short)(u >> 16);
}

__device__ __forceinline__ float gelu_tanh_f(float x) {
    float t = 0.7978845608028654f * (x + 0.044715f * x * x * x);
    float u = 2.0f * t;
    u = fminf(fmaxf(u, -30.0f), 30.0f);
    float e = __expf(u);
    float th = (e - 1.0f) / (e + 1.0f);
    return 0.5f * x * (1.0f + th);
}

// ---------------- conversion: fp32 -> bf16, elementwise ----------------
__global__ void cvt_f32_to_bf16(const float* __restrict__ in,
                                unsigned short* __restrict__ out,
                                long long n) {
    long long i = (long long)blockIdx.x * blockDim.x + threadIdx.x;
    long long stride = (long long)gridDim.x * blockDim.x;
    const float4* in4 = (const float4*)in;
    ushort4* out4 = (ushort4*)out;
    long long n4 = n >> 2;
    for (long long j = i; j < n4; j += stride) {
        float4 v = in4[j];
        ushort4 o;
        o.x = f2bf(v.x); o.y = f2bf(v.y); o.z = f2bf(v.z); o.w = f2bf(v.w);
        out4[j] = o;
    }
}

// ---- transpose + convert: in [E][R][C] fp32 -> out [E][C][R] bf16, 64x64 tiles ----
__global__ void transpose_cvt64(const float* __restrict__ in,
                                unsigned short* __restrict__ out,
                                int R, int C) {
    __shared__ float t[64][65];
    int e = blockIdx.z;
    int c0 = blockIdx.x * 64;
    int r0 = blockIdx.y * 64;
    const float* ine = in + (size_t)e * R * C;
    unsigned short* oute = out + (size_t)e * R * C;
    int tid = threadIdx.x;           // 256
    int lx = tid & 15, ly = tid >> 4;
#pragma unroll
    for (int i = 0; i < 4; i++) {
        float4 v = *(const float4*)(ine + (size_t)(r0 + ly + i * 16) * C + c0 + lx * 4);
        t[lx * 4 + 0][ly + i * 16] = v.x;
        t[lx * 4 + 1][ly + i * 16] = v.y;
        t[lx * 4 + 2][ly + i * 16] = v.z;
        t[lx * 4 + 3][ly + i * 16] = v.w;
    }
    __syncthreads();
#pragma unroll
    for (int i = 0; i < 4; i++) {
        int c = ly + i * 16;
        ushort4 o;
        o.x = f2bf(t[c][lx * 4 + 0]);
        o.y = f2bf(t[c][lx * 4 + 1]);
        o.z = f2bf(t[c][lx * 4 + 2]);
        o.w = f2bf(t[c][lx * 4 + 3]);
        *(ushort4*)(oute + (size_t)(c0 + c) * R + r0 + lx * 4) = o;
    }
}

// =======================================================================
// ROUND 5: 256x128 tile, 8 waves (4M x 2N) each 64x64 (acc[4][4] = 64 AGPR),
// BK=32, 2-buf LDS 48KB, __launch_bounds__(512,4) -> target 2 blocks/CU,
// 4 waves/SIMD. TLP (m114 inter-block overlap) covers the vmcnt(0) drain —
// r2-r4 proved intra-block phase-restructuring is null at 1 block/CU.
//   C[e] = A[e] (MxK) * Bt[e] (NxK)^T
// =======================================================================
__device__ __forceinline__ void gload16(const void* g, void* l) {
    __builtin_amdgcn_global_load_lds((as1cv_t)g, (as3v_t)l, 16, 0, 0);
}

template <int DO_GELU>
__global__ __launch_bounds__(512, 4) void gemm256x128(
    const unsigned short* __restrict__ A,   // [E][M][K] bf16
    const unsigned short* __restrict__ Bt,  // [E][N][K] bf16
    void* __restrict__ Cout,                // [E][M][N] bf16 (gelu) or fp32
    int M, int N, int K, int tiles_m, int per_e, int nwg)
{
    // T1: XCD swizzle (nwg % 8 == 0; per-XCD chunk = one expert here)
    int bid = blockIdx.x;
    int gbid = (bid & 7) * (nwg >> 3) + (bid >> 3);
    int e  = gbid / per_e;
    int t0_ = gbid % per_e;
    int bn = t0_ / tiles_m;   // bm fastest: consecutive blocks share the B panel
    int bm = t0_ % tiles_m;

    const unsigned short* Ae = A  + (size_t)e * M * K + (size_t)bm * 256 * K;
    const unsigned short* Be = Bt + (size_t)e * N * K + (size_t)bn * 128 * K;

    // 2 buffers x (A 16KB | B 8KB) = 48 KiB
    __shared__ alignas(16) unsigned short lds[2 * 12288];
    char* ldsc = (char*)lds;                    // generic: gload_lds dst only
    as3cc_t lbase = (as3cc_t)(const char*)lds;  // addrspace(3): ds_read

    int tid  = threadIdx.x;
    int wid  = tid >> 6;
    int lane = tid & 63;
    int wave_m = wid >> 1;   // 0..3 -> rows wave_m*64
    int wave_n = wid & 1;    // 0..1 -> cols wave_n*64

    // ---- staging (verified swizzle pair from r2-r4) ----
    // chunk c = wid*64 + lane; 16B/chunk; row = c>>2 (64B/row).
    // read-side key = ((row>>1)&3)<<4; source pre-swizzled with same key.
    int c0 = wid * 64 + lane;
    int r0 = c0 >> 2;
    int kb = ((c0 & 3) << 4) ^ (((r0 >> 1) & 3) << 4);
    const char* gA0 = (const char*)(Ae + (size_t)r0 * K) + kb;          // A rows 0..127
    const char* gA1 = (const char*)(Ae + (size_t)(r0 + 128) * K) + kb;  // A rows 128..255
    const char* gB0 = (const char*)(Be + (size_t)r0 * K) + kb;          // B rows 0..127
    int sA = wid << 10;   // wave-uniform LDS stage offset

    // ---- fragment read byte offsets within a buffer ----
    int xk = (((lane & 15) >> 1) & 3) << 4;
    unsigned a_off = (unsigned)((wave_m * 64 + (lane & 15)) * 64 + ((((lane >> 4) << 4)) ^ xk));
    unsigned b_off = 16384u + (unsigned)((wave_n * 64 + (lane & 15)) * 64 + ((((lane >> 4) << 4)) ^ xk));

    f32x4 acc[4][4];
    f32x4 zero = {0.0f, 0.0f, 0.0f, 0.0f};
#pragma unroll
    for (int i = 0; i < 4; i++)
#pragma unroll
        for (int j = 0; j < 4; j++) acc[i][j] = zero;

    int NT = K >> 5;

#define STAGE(dst) do { \
        gload16(gA0, ldsc + (dst) + sA); \
        gload16(gA1, ldsc + (dst) + 8192 + sA); \
        gload16(gB0, ldsc + (dst) + 16384 + sA); \
        gA0 += 64; gA1 += 64; gB0 += 64; } while (0)

    // prologue: stage tile 0
    STAGE(0);
    asm volatile("s_waitcnt vmcnt(0)" ::: "memory");
    __builtin_amdgcn_s_barrier();

    for (int kt = 0; kt < NT; ++kt) {
        unsigned bufC = (unsigned)(kt & 1) * 24576u;
        unsigned bufN = (unsigned)(~kt & 1) * 24576u;
        bool more = (kt + 1) < NT;

        if (more) STAGE(bufN);   // tile kt+1; its dst buffer was fully read at kt-1

        as3cc_t pa = lbase + (bufC + a_off);
        as3cc_t pb = lbase + (bufC + b_off);

        short8 af[4], bf[4];
#pragma unroll
        for (int n = 0; n < 4; ++n) bf[n] = *(as3s8_t)(pb + n * 1024);
#pragma unroll
        for (int m = 0; m < 4; ++m) af[m] = *(as3s8_t)(pa + m * 1024);

        __builtin_amdgcn_s_setprio(1);
#pragma unroll
        for (int m = 0; m < 4; ++m)
#pragma unroll
            for (int n = 0; n < 4; ++n)
                acc[m][n] = __builtin_amdgcn_mfma_f32_16x16x32_bf16(af[m], bf[n], acc[m][n], 0, 0, 0);
        __builtin_amdgcn_s_setprio(0);

        // all waves' stage loads must land before anyone reads bufN next iter.
        // The drain is covered by the co-resident block (m114 TLP).
        if (more) asm volatile("s_waitcnt vmcnt(0)" ::: "memory");
        __builtin_amdgcn_s_barrier();
    }
#undef STAGE

    // epilogue: C/D layout col=lane&15, row=(lane>>4)*4+j
    int row0 = bm * 256 + wave_m * 64 + ((lane >> 4) << 2);
    int col0 = bn * 128 + wave_n * 64 + (lane & 15);
    if (DO_GELU) {
        unsigned short* Ce = (unsigned short*)Cout + (size_t)e * M * N;
#pragma unroll
        for (int m = 0; m < 4; ++m)
#pragma unroll
            for (int n = 0; n < 4; ++n)
#pragma unroll
                for (int j = 0; j < 4; ++j) {
                    int row = row0 + m * 16 + j;
                    int col = col0 + n * 16;
                    Ce[(size_t)row * N + col] = f2bf(gelu_tanh_f(acc[m][n][j]));
                }
    } else {
        float* Ce = (float*)Cout + (size_t)e * M * N;
#pragma unroll
        for (int m = 0; m < 4; ++m)
#pragma unroll
            for (int n = 0; n < 4; ++n)
#pragma unroll
                for (int j = 0; j < 4; ++j) {
                    int row = row0 + m * 16 + j;
                    int col = col0 + n * 16;
                    Ce[(size_t)row * N + col] = acc[m][n][j];
                }
    }
}

extern "C" void kernel_launch(void* const* d_in, const int* in_sizes, int n_in,
                              void* d_out, int out_size, void* d_ws, size_t ws_size,
                              hipStream_t stream) {
    const float* x  = (const float*)d_in[0];   // [E][T][H]
    const float* w1 = (const float*)d_in[1];   // [E][H][F]
    const float* w2 = (const float*)d_in[2];   // [E][F][H]
    float* out = (float*)d_out;                // [E][T][H]

    const int E = 8, T = 2048, H = 1024, F = 4096;

    // workspace (bf16): x | w1^T | w2^T | h   (~302 MiB)
    unsigned short* xb  = (unsigned short*)d_ws;
    unsigned short* w1t = xb  + (size_t)E * T * H;   // [E][F][H]
    unsigned short* w2t = w1t + (size_t)E * H * F;   // [E][H][F]
    unsigned short* hb  = w2t + (size_t)E * F * H;   // [E][T][F]

    cvt_f32_to_bf16<<<2048, 256, 0, stream>>>(x, xb, (long long)E * T * H);

    // w1 [E][H][F] -> w1t [E][F][H];  w2 [E][F][H] -> w2t [E][H][F]
    transpose_cvt64<<<dim3(F / 64, H / 64, E), 256, 0, stream>>>(w1, w1t, H, F);
    transpose_cvt64<<<dim3(H / 64, F / 64, E), 256, 0, stream>>>(w2, w2t, F, H);

    // GEMM1 + GELU: hb[e] = gelu(xb[e] @ w1[e]),  M=2048, N=4096, K=1024
    {
        int M = T, N = F, K = H;
        int tiles_m = M / 256, per_e = tiles_m * (N / 128);   // 8*32 = 256
        int nwg = E * per_e;   // 2048
        gemm256x128<1><<<nwg, 512, 0, stream>>>(xb, w1t, hb, M, N, K, tiles_m, per_e, nwg);
    }
    // GEMM2: out[e] = hb[e] @ w2[e],  M=2048, N=1024, K=4096
    {
        int M = T, N = H, K = F;
        int tiles_m = M / 256, per_e = tiles_m * (N / 128);   // 8*8 = 64
        int nwg = E * per_e;   // 512
        gemm256x128<0><<<nwg, 512, 0, stream>>>(hb, w2t, out, M, N, K, tiles_m, per_e, nwg);
    }
}

// Round 6
// 389.714 us; speedup vs baseline: 1.1107x; 1.1107x over previous
//
#include <hip/hip_runtime.h>
#include <hip/hip_bf16.h>

typedef __attribute__((ext_vector_type(8))) short short8;
typedef __attribute__((ext_vector_type(4))) float f32x4;

typedef const __attribute__((address_space(1))) void* as1cv_t;
typedef __attribute__((address_space(3))) void* as3v_t;
typedef __attribute__((address_space(3))) const char* as3cc_t;
typedef __attribute__((address_space(3))) const short8* as3s8_t;

__device__ __forceinline__ unsigned short f2bf(float f) {
    unsigned u = __float_as_uint(f);
    u += 0x7fffu + ((u >> 16) & 1u);   // round-to-nearest-even
    return (unsigned short)(u >> 16);
}

__device__ __forceinline__ float gelu_tanh_f(float x) {
    float t = 0.7978845608028654f * (x + 0.044715f * x * x * x);
    float u = 2.0f * t;
    u = fminf(fmaxf(u, -30.0f), 30.0f);
    float e = __expf(u);
    float th = (e - 1.0f) / (e + 1.0f);
    return 0.5f * x * (1.0f + th);
}

// ---------------- conversion: fp32 -> bf16, elementwise ----------------
__global__ void cvt_f32_to_bf16(const float* __restrict__ in,
                                unsigned short* __restrict__ out,
                                long long n) {
    long long i = (long long)blockIdx.x * blockDim.x + threadIdx.x;
    long long stride = (long long)gridDim.x * blockDim.x;
    const float4* in4 = (const float4*)in;
    ushort4* out4 = (ushort4*)out;
    long long n4 = n >> 2;
    for (long long j = i; j < n4; j += stride) {
        float4 v = in4[j];
        ushort4 o;
        o.x = f2bf(v.x); o.y = f2bf(v.y); o.z = f2bf(v.z); o.w = f2bf(v.w);
        out4[j] = o;
    }
}

// ---- transpose + convert: in [E][R][C] fp32 -> out [E][C][R] bf16, 64x64 tiles ----
__global__ void transpose_cvt64(const float* __restrict__ in,
                                unsigned short* __restrict__ out,
                                int R, int C) {
    __shared__ float t[64][65];
    int e = blockIdx.z;
    int c0 = blockIdx.x * 64;
    int r0 = blockIdx.y * 64;
    const float* ine = in + (size_t)e * R * C;
    unsigned short* oute = out + (size_t)e * R * C;
    int tid = threadIdx.x;           // 256
    int lx = tid & 15, ly = tid >> 4;
#pragma unroll
    for (int i = 0; i < 4; i++) {
        float4 v = *(const float4*)(ine + (size_t)(r0 + ly + i * 16) * C + c0 + lx * 4);
        t[lx * 4 + 0][ly + i * 16] = v.x;
        t[lx * 4 + 1][ly + i * 16] = v.y;
        t[lx * 4 + 2][ly + i * 16] = v.z;
        t[lx * 4 + 3][ly + i * 16] = v.w;
    }
    __syncthreads();
#pragma unroll
    for (int i = 0; i < 4; i++) {
        int c = ly + i * 16;
        ushort4 o;
        o.x = f2bf(t[c][lx * 4 + 0]);
        o.y = f2bf(t[c][lx * 4 + 1]);
        o.z = f2bf(t[c][lx * 4 + 2]);
        o.w = f2bf(t[c][lx * 4 + 3]);
        *(ushort4*)(oute + (size_t)(c0 + c) * R + r0 + lx * 4) = o;
    }
}

// =======================================================================
// ROUND 6: m201-style 8-phase schedule. 256x256 tile, BK=64, 8 waves
// (2M x 4N), per-wave 128x64 = acc[8][4]. LDS 2 x 64KB = [A0|A1|B0|B1].
// Per K64-tile: 4 phases {reads + stage-1-half-tile -> BAR -> 16 MFMA -> BAR},
// quadrant order (mlo,nlo)(mlo,nhi)(mhi,nhi)(mhi,nlo), reads 12/4/8/0 with
// operand reuse. Stage schedule: P1->A0(t+1) P2->A1(t+1) P3->B0(t+2)
// P4->B1(t+2). ONE counted vmcnt(4) per K-tile at P4 (retires t+1, keeps
// B(t+2) flying). Swizzle (128B rows): slot' = slot ^ (row&7).
// =======================================================================
__device__ __forceinline__ void gload16(const void* g, void* l) {
    __builtin_amdgcn_global_load_lds((as1cv_t)g, (as3v_t)l, 16, 0, 0);
}

#define MFMA_BF16 __builtin_amdgcn_mfma_f32_16x16x32_bf16

template <int DO_GELU>
__global__ __launch_bounds__(512, 2) void gemm8p(
    const unsigned short* __restrict__ A,   // [E][M][K] bf16
    const unsigned short* __restrict__ Bt,  // [E][N][K] bf16
    void* __restrict__ Cout,                // [E][M][N] bf16 (gelu) or fp32
    int M, int N, int K, int tiles_m, int per_e, int nwg)
{
    // T1: XCD swizzle (nwg % 8 == 0)
    int bid = blockIdx.x;
    int gbid = (bid & 7) * (nwg >> 3) + (bid >> 3);
    int e  = gbid / per_e;
    int t0_ = gbid % per_e;
    int bn = t0_ / tiles_m;
    int bm = t0_ % tiles_m;

    const size_t K2 = (size_t)K * 2;
    const char* Ae = (const char*)A  + ((size_t)e * M * K + (size_t)bm * 256 * K) * 2;
    const char* Be = (const char*)Bt + ((size_t)e * N * K + (size_t)bn * 256 * K) * 2;

    __shared__ alignas(16) unsigned short lds[2 * 32768];   // 128 KiB
    char* ldsc = (char*)lds;
    as3cc_t lb = (as3cc_t)(const char*)lds;

    int tid  = threadIdx.x;
    int wid  = tid >> 6;
    int lane = tid & 63;
    int wave_m = wid >> 2;   // 0..1 -> rows wave_m*128
    int wave_n = wid & 3;    // 0..3 -> cols wave_n*64

    // ---- staging: chunk c = wid*64+lane (+512/round); row=c>>3 (128B/row), slot=c&7
    // read-side swizzle slot' = slot ^ (row&7)  => source pre-swizzled (involution)
    int srow = wid * 8 + (lane >> 3);                       // 0..63 (round 0)
    int kbsw = ((lane & 7) ^ (srow & 7)) << 4;
    const char* gA = Ae + (size_t)srow * K2 + kbsw;
    const char* gB = Be + (size_t)srow * K2 + kbsw;
    const size_t HROW = 64 * K2;    // round 1: +64 rows
    const size_t HALF = 128 * K2;   // half 1: +128 rows
    int sOff = wid << 10;           // uniform LDS offset inside a half-tile region

    // ---- fragment read offsets (bytes) ----
    unsigned kg   = (unsigned)(lane >> 4);            // k-group 0..3
    unsigned keyl = (unsigned)(lane & 7) & 7u;        // (row&7), row=(lane&15)+16m
    keyl = (unsigned)((lane & 15) & 7);
    unsigned sl0  = (kg ^ keyl) << 4;                 // ks=0 slot-byte (ks=1 = ^64)
    unsigned aoff = (unsigned)(wave_m * 16384 + (lane & 15) * 128) + sl0;
    unsigned boff = 32768u + (unsigned)((wave_n >> 1) * 16384 +
                    ((wave_n & 1) * 64 + (lane & 15)) * 128) + sl0;

    f32x4 acc[8][4];
    f32x4 zero = {0.0f, 0.0f, 0.0f, 0.0f};
#pragma unroll
    for (int i = 0; i < 8; i++)
#pragma unroll
        for (int j = 0; j < 4; j++) acc[i][j] = zero;

    int NT = K >> 6;

    // stage one half-tile round: h in {0,1}, r in {0,1}, bufbit in {0,1}
#define STG_A(h, r, bufbit) gload16(gA + (h) * HALF + (r) * HROW, \
        ldsc + ((bufbit) << 16) + (h) * 16384 + (r) * 8192 + sOff)
#define STG_B(h, r, bufbit) gload16(gB + (h) * HALF + (r) * HROW, \
        ldsc + ((bufbit) << 16) + 32768 + (h) * 16384 + (r) * 8192 + sOff)

    // prologue: A(0),B(0) -> buf0; B(1) -> buf1. 12 loads; tile0 = oldest 8.
    STG_A(0, 0, 0); STG_A(0, 1, 0); STG_A(1, 0, 0); STG_A(1, 1, 0);
    STG_B(0, 0, 0); STG_B(0, 1, 0); STG_B(1, 0, 0); STG_B(1, 1, 0);
    gB += 128;
    if (NT > 1) {
        STG_B(0, 0, 1); STG_B(0, 1, 1); STG_B(1, 0, 1); STG_B(1, 1, 1);
        asm volatile("s_waitcnt vmcnt(4)" ::: "memory");
    } else {
        asm volatile("s_waitcnt vmcnt(0)" ::: "memory");
    }
    gB += 128;
    gA += 128;
    __builtin_amdgcn_s_barrier();

    for (int t = 0; t < NT; ++t) {
        unsigned bufR = (unsigned)(t & 1) << 16;
        int wbA = (t + 1) & 1;
        int wbB = t & 1;
        bool stA = (t + 1) < NT;
        bool stB = (t + 2) < NT;

        unsigned pa0 = bufR + aoff, pa1 = pa0 ^ 64u;
        unsigned pb0 = bufR + boff, pb1 = pb0 ^ 64u;

        short8 aL[4][2], aH[4][2], bL[2][2], bH[2][2];

        // ======== phase 1: read A[m0-3]x2k (8) + B[n0-1]x2k (4); stage A0(t+1)
#pragma unroll
        for (int mi = 0; mi < 4; ++mi) {
            aL[mi][0] = *(as3s8_t)(lb + (pa0 + mi * 2048));
            aL[mi][1] = *(as3s8_t)(lb + (pa1 + mi * 2048));
        }
#pragma unroll
        for (int ni = 0; ni < 2; ++ni) {
            bL[ni][0] = *(as3s8_t)(lb + (pb0 + ni * 2048));
            bL[ni][1] = *(as3s8_t)(lb + (pb1 + ni * 2048));
        }
        if (stA) { STG_A(0, 0, wbA); STG_A(0, 1, wbA); }
        __builtin_amdgcn_sched_barrier(0);
        __builtin_amdgcn_s_barrier();
        __builtin_amdgcn_s_setprio(1);
#pragma unroll
        for (int ks = 0; ks < 2; ++ks)
#pragma unroll
            for (int mi = 0; mi < 4; ++mi)
#pragma unroll
                for (int ni = 0; ni < 2; ++ni)
                    acc[mi][ni] = MFMA_BF16(aL[mi][ks], bL[ni][ks], acc[mi][ni], 0, 0, 0);
        __builtin_amdgcn_s_setprio(0);
        __builtin_amdgcn_sched_barrier(0);
        __builtin_amdgcn_s_barrier();

        // ======== phase 2: read B[n2-3]x2k (4); stage A1(t+1); advance gA
#pragma unroll
        for (int ni = 0; ni < 2; ++ni) {
            bH[ni][0] = *(as3s8_t)(lb + (pb0 + (2 + ni) * 2048));
            bH[ni][1] = *(as3s8_t)(lb + (pb1 + (2 + ni) * 2048));
        }
        if (stA) { STG_A(1, 0, wbA); STG_A(1, 1, wbA); }
        gA += 128;
        __builtin_amdgcn_sched_barrier(0);
        __builtin_amdgcn_s_barrier();
        __builtin_amdgcn_s_setprio(1);
#pragma unroll
        for (int ks = 0; ks < 2; ++ks)
#pragma unroll
            for (int mi = 0; mi < 4; ++mi)
#pragma unroll
                for (int ni = 0; ni < 2; ++ni)
                    acc[mi][2 + ni] = MFMA_BF16(aL[mi][ks], bH[ni][ks], acc[mi][2 + ni], 0, 0, 0);
        __builtin_amdgcn_s_setprio(0);
        __builtin_amdgcn_sched_barrier(0);
        __builtin_amdgcn_s_barrier();

        // ======== phase 3: read A[m4-7]x2k (8); stage B0(t+2)
        // (B0(t) fully consumed at phase 2; stage issues after its barrier)
#pragma unroll
        for (int mi = 0; mi < 4; ++mi) {
            aH[mi][0] = *(as3s8_t)(lb + (pa0 + (4 + mi) * 2048));
            aH[mi][1] = *(as3s8_t)(lb + (pa1 + (4 + mi) * 2048));
        }
        if (stB) { STG_B(0, 0, wbB); STG_B(0, 1, wbB); }
        __builtin_amdgcn_sched_barrier(0);
        __builtin_amdgcn_s_barrier();
        __builtin_amdgcn_s_setprio(1);
#pragma unroll
        for (int ks = 0; ks < 2; ++ks)
#pragma unroll
            for (int mi = 0; mi < 4; ++mi)
#pragma unroll
                for (int ni = 0; ni < 2; ++ni)
                    acc[4 + mi][2 + ni] = MFMA_BF16(aH[mi][ks], bH[ni][ks], acc[4 + mi][2 + ni], 0, 0, 0);
        __builtin_amdgcn_s_setprio(0);
        __builtin_amdgcn_sched_barrier(0);
        __builtin_amdgcn_s_barrier();

        // ======== phase 4: no reads; stage B1(t+2); advance gB; counted vmcnt
        // ledger: [B(t+1):4 oldest | A(t+1):4 | B(t+2):4 newest] -> vmcnt(4)
        // retires all of tile t+1, keeps B(t+2) in flight across the barrier.
        if (stB) { STG_B(1, 0, wbB); STG_B(1, 1, wbB); }
        gB += 128;
        if (stB) asm volatile("s_waitcnt vmcnt(4)" ::: "memory");
        else     asm volatile("s_waitcnt vmcnt(0)" ::: "memory");
        __builtin_amdgcn_sched_barrier(0);
        __builtin_amdgcn_s_barrier();
        __builtin_amdgcn_s_setprio(1);
#pragma unroll
        for (int ks = 0; ks < 2; ++ks)
#pragma unroll
            for (int mi = 0; mi < 4; ++mi)
#pragma unroll
                for (int ni = 0; ni < 2; ++ni)
                    acc[4 + mi][ni] = MFMA_BF16(aH[mi][ks], bL[ni][ks], acc[4 + mi][ni], 0, 0, 0);
        __builtin_amdgcn_s_setprio(0);
        __builtin_amdgcn_sched_barrier(0);
        __builtin_amdgcn_s_barrier();
    }
#undef STG_A
#undef STG_B

    // epilogue: C/D layout col=lane&15, row=(lane>>4)*4+j
    int row0 = bm * 256 + wave_m * 128 + ((lane >> 4) << 2);
    int col0 = bn * 256 + wave_n * 64 + (lane & 15);
    if (DO_GELU) {
        unsigned short* Ce = (unsigned short*)Cout + (size_t)e * M * N;
#pragma unroll
        for (int m = 0; m < 8; ++m)
#pragma unroll
            for (int n = 0; n < 4; ++n)
#pragma unroll
                for (int j = 0; j < 4; ++j) {
                    int row = row0 + m * 16 + j;
                    int col = col0 + n * 16;
                    Ce[(size_t)row * N + col] = f2bf(gelu_tanh_f(acc[m][n][j]));
                }
    } else {
        float* Ce = (float*)Cout + (size_t)e * M * N;
#pragma unroll
        for (int m = 0; m < 8; ++m)
#pragma unroll
            for (int n = 0; n < 4; ++n)
#pragma unroll
                for (int j = 0; j < 4; ++j) {
                    int row = row0 + m * 16 + j;
                    int col = col0 + n * 16;
                    Ce[(size_t)row * N + col] = acc[m][n][j];
                }
    }
}

extern "C" void kernel_launch(void* const* d_in, const int* in_sizes, int n_in,
                              void* d_out, int out_size, void* d_ws, size_t ws_size,
                              hipStream_t stream) {
    const float* x  = (const float*)d_in[0];   // [E][T][H]
    const float* w1 = (const float*)d_in[1];   // [E][H][F]
    const float* w2 = (const float*)d_in[2];   // [E][F][H]
    float* out = (float*)d_out;                // [E][T][H]

    const int E = 8, T = 2048, H = 1024, F = 4096;

    // workspace (bf16): x | w1^T | w2^T | h   (~302 MiB)
    unsigned short* xb  = (unsigned short*)d_ws;
    unsigned short* w1t = xb  + (size_t)E * T * H;   // [E][F][H]
    unsigned short* w2t = w1t + (size_t)E * H * F;   // [E][H][F]
    unsigned short* hb  = w2t + (size_t)E * F * H;   // [E][T][F]

    cvt_f32_to_bf16<<<2048, 256, 0, stream>>>(x, xb, (long long)E * T * H);

    // w1 [E][H][F] -> w1t [E][F][H];  w2 [E][F][H] -> w2t [E][H][F]
    transpose_cvt64<<<dim3(F / 64, H / 64, E), 256, 0, stream>>>(w1, w1t, H, F);
    transpose_cvt64<<<dim3(H / 64, F / 64, E), 256, 0, stream>>>(w2, w2t, F, H);

    // GEMM1 + GELU: hb[e] = gelu(xb[e] @ w1[e]),  M=2048, N=4096, K=1024
    {
        int M = T, N = F, K = H;
        int tiles_m = M / 256, per_e = tiles_m * (N / 256);  // 8*16 = 128
        int nwg = E * per_e;   // 1024
        gemm8p<1><<<nwg, 512, 0, stream>>>(xb, w1t, hb, M, N, K, tiles_m, per_e, nwg);
    }
    // GEMM2: out[e] = hb[e] @ w2[e],  M=2048, N=1024, K=4096
    {
        int M = T, N = H, K = F;
        int tiles_m = M / 256, per_e = tiles_m * (N / 256);  // 8*4 = 32
        int nwg = E * per_e;   // 256
        gemm8p<0><<<nwg, 512, 0, stream>>>(hb, w2t, out, M, N, K, tiles_m, per_e, nwg);
    }
}

// Round 7
// 386.818 us; speedup vs baseline: 1.1190x; 1.0075x over previous
//
#include <hip/hip_runtime.h>
#include <hip/hip_bf16.h>

typedef __attribute__((ext_vector_type(8))) short short8;
typedef __attribute__((ext_vector_type(4))) float f32x4;

typedef const __attribute__((address_space(1))) void* as1cv_t;
typedef __attribute__((address_space(3))) void* as3v_t;
typedef __attribute__((address_space(3))) const char* as3cc_t;
typedef __attribute__((address_space(3))) const short8* as3s8_t;

__device__ __forceinline__ unsigned short f2bf(float f) {
    unsigned u = __float_as_uint(f);
    u += 0x7fffu + ((u >> 16) & 1u);   // round-to-nearest-even
    return (unsigned short)(u >> 16);
}

__device__ __forceinline__ float gelu_tanh_f(float x) {
    float t = 0.7978845608028654f * (x + 0.044715f * x * x * x);
    float u = 2.0f * t;
    u = fminf(fmaxf(u, -30.0f), 30.0f);
    float e = __expf(u);
    float th = (e - 1.0f) / (e + 1.0f);
    return 0.5f * x * (1.0f + th);
}

// ---------------- conversion: fp32 -> bf16, elementwise ----------------
__global__ void cvt_f32_to_bf16(const float* __restrict__ in,
                                unsigned short* __restrict__ out,
                                long long n) {
    long long i = (long long)blockIdx.x * blockDim.x + threadIdx.x;
    long long stride = (long long)gridDim.x * blockDim.x;
    const float4* in4 = (const float4*)in;
    ushort4* out4 = (ushort4*)out;
    long long n4 = n >> 2;
    for (long long j = i; j < n4; j += stride) {
        float4 v = in4[j];
        ushort4 o;
        o.x = f2bf(v.x); o.y = f2bf(v.y); o.z = f2bf(v.z); o.w = f2bf(v.w);
        out4[j] = o;
    }
}

// ---- transpose + convert: in [E][R][C] fp32 -> out [E][C][R] bf16, 64x64 tiles ----
__global__ void transpose_cvt64(const float* __restrict__ in,
                                unsigned short* __restrict__ out,
                                int R, int C) {
    __shared__ float t[64][65];
    int e = blockIdx.z;
    int c0 = blockIdx.x * 64;
    int r0 = blockIdx.y * 64;
    const float* ine = in + (size_t)e * R * C;
    unsigned short* oute = out + (size_t)e * R * C;
    int tid = threadIdx.x;           // 256
    int lx = tid & 15, ly = tid >> 4;
#pragma unroll
    for (int i = 0; i < 4; i++) {
        float4 v = *(const float4*)(ine + (size_t)(r0 + ly + i * 16) * C + c0 + lx * 4);
        t[lx * 4 + 0][ly + i * 16] = v.x;
        t[lx * 4 + 1][ly + i * 16] = v.y;
        t[lx * 4 + 2][ly + i * 16] = v.z;
        t[lx * 4 + 3][ly + i * 16] = v.w;
    }
    __syncthreads();
#pragma unroll
    for (int i = 0; i < 4; i++) {
        int c = ly + i * 16;
        ushort4 o;
        o.x = f2bf(t[c][lx * 4 + 0]);
        o.y = f2bf(t[c][lx * 4 + 1]);
        o.z = f2bf(t[c][lx * 4 + 2]);
        o.w = f2bf(t[c][lx * 4 + 3]);
        *(ushort4*)(oute + (size_t)(c0 + c) * R + r0 + lx * 4) = o;
    }
}

// =======================================================================
// ROUND 7: persistent 8-phase GEMM. Each wg owns (e, bn, ROUNDS bm-tiles)
// and runs ONE continuous K-pipeline over ROUNDS*KT tiles: A-pointer jumps
// panels at round boundaries, B-pointer wraps (panel re-read from L2),
// per-round GELU epilogue runs inside the loop with prefetch in flight
// (raw s_barrier does not drain vmcnt; stores retire in background).
// Staging ledger identical to r6: P1/P2 stage A(t+1), P3/P4 stage B(t+2),
// single counted vmcnt(4) per tile at P4.
// =======================================================================
__device__ __forceinline__ void gload16(const void* g, void* l) {
    __builtin_amdgcn_global_load_lds((as1cv_t)g, (as3v_t)l, 16, 0, 0);
}

#define MFMA_BF16 __builtin_amdgcn_mfma_f32_16x16x32_bf16

template <int DO_GELU, int ROUNDS>
__device__ __forceinline__ void gemm_body(
    const unsigned short* __restrict__ A,   // [E][M][K] bf16
    const unsigned short* __restrict__ Bt,  // [E][N][K] bf16
    void* __restrict__ Cout,                // [E][M][N] bf16 (gelu) or fp32
    int M, int N, int K, int bmw_count, int per_e, int nwg)
{
    // T1: XCD swizzle (nwg % 8 == 0)
    int bid = blockIdx.x;
    int gbid = (bid & 7) * (nwg >> 3) + (bid >> 3);
    int e  = gbid / per_e;
    int t0_ = gbid % per_e;
    int bn  = t0_ / bmw_count;
    int sub = t0_ % bmw_count;
    int bm0 = sub * ROUNDS;

    const size_t K2 = (size_t)K * 2;
    const char* Ae = (const char*)A  + ((size_t)e * M * K + (size_t)bm0 * 256 * K) * 2;
    const char* Be = (const char*)Bt + ((size_t)e * N * K + (size_t)bn  * 256 * K) * 2;

    __shared__ alignas(16) unsigned short lds[2 * 32768];   // 128 KiB
    char* ldsc = (char*)lds;
    as3cc_t lb = (as3cc_t)(const char*)lds;

    int tid  = threadIdx.x;
    int wid  = tid >> 6;
    int lane = tid & 63;
    int wave_m = wid >> 2;   // 0..1 -> rows wave_m*128
    int wave_n = wid & 3;    // 0..3 -> cols wave_n*64

    // staging: chunk c = wid*64+lane; row=c>>3 (128B/row), slot=c&7
    // read-side swizzle slot' = slot ^ (row&7) => source pre-swizzled (involution)
    int srow = wid * 8 + (lane >> 3);
    int kbsw = ((lane & 7) ^ (srow & 7)) << 4;
    const char* gA = Ae + (size_t)srow * K2 + kbsw;
    const char* gB = Be + (size_t)srow * K2 + kbsw;
    const size_t HROW = 64 * K2;
    const size_t HALF = 128 * K2;
    int sOff = wid << 10;

    // fragment read offsets (bytes)
    unsigned kg   = (unsigned)(lane >> 4);
    unsigned keyl = (unsigned)((lane & 15) & 7);
    unsigned sl0  = (kg ^ keyl) << 4;
    unsigned aoff = (unsigned)(wave_m * 16384 + (lane & 15) * 128) + sl0;
    unsigned boff = 32768u + (unsigned)((wave_n >> 1) * 16384 +
                    ((wave_n & 1) * 64 + (lane & 15)) * 128) + sl0;

    f32x4 acc[8][4];
    f32x4 zero = {0.0f, 0.0f, 0.0f, 0.0f};
#pragma unroll
    for (int i = 0; i < 8; i++)
#pragma unroll
        for (int j = 0; j < 4; j++) acc[i][j] = zero;

    const int KT = K >> 6;
    const int NT_TOT = ROUNDS * KT;
    const size_t AROUND = 255 * K2;   // from (r,KT-1)+128: -K2 back to kt0, +256*K2 next panel

    int kA = 0, kB = 0;               // staged-tile kt counters (uniform)
#define ADV_A() do { gA += 128; if (++kA == KT) { kA = 0; gA += AROUND; } } while (0)
#define ADV_B() do { gB += 128; if (++kB == KT) { kB = 0; gB -= K2; } } while (0)

#define STG_A(h, r, bufbit) gload16(gA + (h) * HALF + (r) * HROW, \
        ldsc + ((bufbit) << 16) + (h) * 16384 + (r) * 8192 + sOff)
#define STG_B(h, r, bufbit) gload16(gB + (h) * HALF + (r) * HROW, \
        ldsc + ((bufbit) << 16) + 32768 + (h) * 16384 + (r) * 8192 + sOff)

    // prologue: A(0),B(0) -> buf0; B(1) -> buf1; keep B(1) in flight.
    STG_A(0, 0, 0); STG_A(0, 1, 0); STG_A(1, 0, 0); STG_A(1, 1, 0);
    STG_B(0, 0, 0); STG_B(0, 1, 0); STG_B(1, 0, 0); STG_B(1, 1, 0);
    ADV_B();
    if (NT_TOT > 1) {
        STG_B(0, 0, 1); STG_B(0, 1, 1); STG_B(1, 0, 1); STG_B(1, 1, 1);
        asm volatile("s_waitcnt vmcnt(4)" ::: "memory");
    } else {
        asm volatile("s_waitcnt vmcnt(0)" ::: "memory");
    }
    ADV_B();
    ADV_A();
    __builtin_amdgcn_s_barrier();

    int ktEp = 0, rEp = 0;            // in-loop epilogue bookkeeping

    for (int t = 0; t < NT_TOT; ++t) {
        unsigned bufR = (unsigned)(t & 1) << 16;
        int wbA = (t + 1) & 1;
        int wbB = t & 1;
        bool stA = (t + 1) < NT_TOT;
        bool stB = (t + 2) < NT_TOT;

        unsigned pa0 = bufR + aoff, pa1 = pa0 ^ 64u;
        unsigned pb0 = bufR + boff, pb1 = pb0 ^ 64u;

        short8 aL[4][2], aH[4][2], bL[2][2], bH[2][2];

        // ==== phase 1: read A[m0-3] (8) + B[n0-1] (4); stage A0(t+1)
#pragma unroll
        for (int mi = 0; mi < 4; ++mi) {
            aL[mi][0] = *(as3s8_t)(lb + (pa0 + mi * 2048));
            aL[mi][1] = *(as3s8_t)(lb + (pa1 + mi * 2048));
        }
#pragma unroll
        for (int ni = 0; ni < 2; ++ni) {
            bL[ni][0] = *(as3s8_t)(lb + (pb0 + ni * 2048));
            bL[ni][1] = *(as3s8_t)(lb + (pb1 + ni * 2048));
        }
        if (stA) { STG_A(0, 0, wbA); STG_A(0, 1, wbA); }
        __builtin_amdgcn_sched_barrier(0);
        __builtin_amdgcn_s_barrier();
        __builtin_amdgcn_s_setprio(1);
#pragma unroll
        for (int ks = 0; ks < 2; ++ks)
#pragma unroll
            for (int mi = 0; mi < 4; ++mi)
#pragma unroll
                for (int ni = 0; ni < 2; ++ni)
                    acc[mi][ni] = MFMA_BF16(aL[mi][ks], bL[ni][ks], acc[mi][ni], 0, 0, 0);
        __builtin_amdgcn_s_setprio(0);
        __builtin_amdgcn_sched_barrier(0);
        __builtin_amdgcn_s_barrier();

        // ==== phase 2: read B[n2-3] (4); stage A1(t+1); advance A
#pragma unroll
        for (int ni = 0; ni < 2; ++ni) {
            bH[ni][0] = *(as3s8_t)(lb + (pb0 + (2 + ni) * 2048));
            bH[ni][1] = *(as3s8_t)(lb + (pb1 + (2 + ni) * 2048));
        }
        if (stA) { STG_A(1, 0, wbA); STG_A(1, 1, wbA); }
        ADV_A();
        __builtin_amdgcn_sched_barrier(0);
        __builtin_amdgcn_s_barrier();
        __builtin_amdgcn_s_setprio(1);
#pragma unroll
        for (int ks = 0; ks < 2; ++ks)
#pragma unroll
            for (int mi = 0; mi < 4; ++mi)
#pragma unroll
                for (int ni = 0; ni < 2; ++ni)
                    acc[mi][2 + ni] = MFMA_BF16(aL[mi][ks], bH[ni][ks], acc[mi][2 + ni], 0, 0, 0);
        __builtin_amdgcn_s_setprio(0);
        __builtin_amdgcn_sched_barrier(0);
        __builtin_amdgcn_s_barrier();

        // ==== phase 3: read A[m4-7] (8); stage B0(t+2)
#pragma unroll
        for (int mi = 0; mi < 4; ++mi) {
            aH[mi][0] = *(as3s8_t)(lb + (pa0 + (4 + mi) * 2048));
            aH[mi][1] = *(as3s8_t)(lb + (pa1 + (4 + mi) * 2048));
        }
        if (stB) { STG_B(0, 0, wbB); STG_B(0, 1, wbB); }
        __builtin_amdgcn_sched_barrier(0);
        __builtin_amdgcn_s_barrier();
        __builtin_amdgcn_s_setprio(1);
#pragma unroll
        for (int ks = 0; ks < 2; ++ks)
#pragma unroll
            for (int mi = 0; mi < 4; ++mi)
#pragma unroll
                for (int ni = 0; ni < 2; ++ni)
                    acc[4 + mi][2 + ni] = MFMA_BF16(aH[mi][ks], bH[ni][ks], acc[4 + mi][2 + ni], 0, 0, 0);
        __builtin_amdgcn_s_setprio(0);
        __builtin_amdgcn_sched_barrier(0);
        __builtin_amdgcn_s_barrier();

        // ==== phase 4: stage B1(t+2); advance B; ONE counted vmcnt
        // ledger: [B(t+1):4 | A(t+1):4 | B(t+2):4] -> vmcnt(4) retires tile t+1
        if (stB) { STG_B(1, 0, wbB); STG_B(1, 1, wbB); }
        ADV_B();
        if (stB) asm volatile("s_waitcnt vmcnt(4)" ::: "memory");
        else     asm volatile("s_waitcnt vmcnt(0)" ::: "memory");
        __builtin_amdgcn_sched_barrier(0);
        __builtin_amdgcn_s_barrier();
        __builtin_amdgcn_s_setprio(1);
#pragma unroll
        for (int ks = 0; ks < 2; ++ks)
#pragma unroll
            for (int mi = 0; mi < 4; ++mi)
#pragma unroll
                for (int ni = 0; ni < 2; ++ni)
                    acc[4 + mi][ni] = MFMA_BF16(aH[mi][ks], bL[ni][ks], acc[4 + mi][ni], 0, 0, 0);
        __builtin_amdgcn_s_setprio(0);
        __builtin_amdgcn_sched_barrier(0);
        __builtin_amdgcn_s_barrier();

        // ==== per-round epilogue (inside loop; prefetch stays in flight) ====
        if (++ktEp == KT) {
            ktEp = 0;
            int row0 = (bm0 + rEp) * 256 + wave_m * 128 + ((lane >> 4) << 2);
            int col0 = bn * 256 + wave_n * 64 + (lane & 15);
            if (DO_GELU) {
                unsigned short* Ce = (unsigned short*)Cout + (size_t)e * M * N;
#pragma unroll
                for (int m = 0; m < 8; ++m)
#pragma unroll
                    for (int n = 0; n < 4; ++n)
#pragma unroll
                        for (int j = 0; j < 4; ++j) {
                            int row = row0 + m * 16 + j;
                            int col = col0 + n * 16;
                            Ce[(size_t)row * N + col] = f2bf(gelu_tanh_f(acc[m][n][j]));
                        }
            } else {
                float* Ce = (float*)Cout + (size_t)e * M * N;
#pragma unroll
                for (int m = 0; m < 8; ++m)
#pragma unroll
                    for (int n = 0; n < 4; ++n)
#pragma unroll
                        for (int j = 0; j < 4; ++j) {
                            int row = row0 + m * 16 + j;
                            int col = col0 + n * 16;
                            Ce[(size_t)row * N + col] = acc[m][n][j];
                        }
            }
            rEp++;
#pragma unroll
            for (int i = 0; i < 8; i++)
#pragma unroll
                for (int j = 0; j < 4; j++) acc[i][j] = zero;
        }
    }
#undef STG_A
#undef STG_B
#undef ADV_A
#undef ADV_B
}

__global__ __launch_bounds__(512, 2) void gemm_mlp1(
    const unsigned short* __restrict__ A, const unsigned short* __restrict__ Bt,
    void* __restrict__ C, int M, int N, int K, int bmw, int per_e, int nwg) {
    gemm_body<1, 4>(A, Bt, C, M, N, K, bmw, per_e, nwg);
}
__global__ __launch_bounds__(512, 2) void gemm_mlp2(
    const unsigned short* __restrict__ A, const unsigned short* __restrict__ Bt,
    void* __restrict__ C, int M, int N, int K, int bmw, int per_e, int nwg) {
    gemm_body<0, 1>(A, Bt, C, M, N, K, bmw, per_e, nwg);
}

extern "C" void kernel_launch(void* const* d_in, const int* in_sizes, int n_in,
                              void* d_out, int out_size, void* d_ws, size_t ws_size,
                              hipStream_t stream) {
    const float* x  = (const float*)d_in[0];   // [E][T][H]
    const float* w1 = (const float*)d_in[1];   // [E][H][F]
    const float* w2 = (const float*)d_in[2];   // [E][F][H]
    float* out = (float*)d_out;                // [E][T][H]

    const int E = 8, T = 2048, H = 1024, F = 4096;

    // workspace (bf16): x | w1^T | w2^T | h   (~302 MiB)
    unsigned short* xb  = (unsigned short*)d_ws;
    unsigned short* w1t = xb  + (size_t)E * T * H;   // [E][F][H]
    unsigned short* w2t = w1t + (size_t)E * H * F;   // [E][H][F]
    unsigned short* hb  = w2t + (size_t)E * F * H;   // [E][T][F]

    cvt_f32_to_bf16<<<2048, 256, 0, stream>>>(x, xb, (long long)E * T * H);

    // w1 [E][H][F] -> w1t [E][F][H];  w2 [E][F][H] -> w2t [E][H][F]
    transpose_cvt64<<<dim3(F / 64, H / 64, E), 256, 0, stream>>>(w1, w1t, H, F);
    transpose_cvt64<<<dim3(H / 64, F / 64, E), 256, 0, stream>>>(w2, w2t, F, H);

    // GEMM1 + GELU: hb[e] = gelu(xb[e] @ w1[e]),  M=2048, N=4096, K=1024
    // per wg: 1 bn x 4 bm-tiles => 64 K-tiles persistent. nwg = 8e*16bn*2 = 256.
    {
        int M_ = T, N_ = F, K_ = H;
        int bmw = (M_ / 256) / 4;          // 2
        int per_e = (N_ / 256) * bmw;      // 32
        int nwg = E * per_e;               // 256
        gemm_mlp1<<<nwg, 512, 0, stream>>>(xb, w1t, hb, M_, N_, K_, bmw, per_e, nwg);
    }
    // GEMM2: out[e] = hb[e] @ w2[e],  M=2048, N=1024, K=4096 (64 K-tiles native)
    {
        int M_ = T, N_ = H, K_ = F;
        int bmw = M_ / 256;                // 8
        int per_e = (N_ / 256) * bmw;      // 32
        int nwg = E * per_e;               // 256
        gemm_mlp2<<<nwg, 512, 0, stream>>>(hb, w2t, out, M_, N_, K_, bmw, per_e, nwg);
    }
}